// Round 4
// baseline (1012.615 us; speedup 1.0000x reference)
//
#include <hip/hip_runtime.h>
#include <stdint.h>
#include <math.h>

// Problem dims
#define T_ 4
#define B_ 8
#define C_ 256
#define N_ 2048
#define TB_ 32          // T_*B_
#define H_ 16
#define D_ 16
#define NTOT 65536      // T_*B_*N_  (BN reduction count per channel)
#define EPS 1e-5
#define NSLOT 1024      // per-channel partial-stat slots = n_blocks(32) * tb(32)

typedef double v4d __attribute__((ext_vector_type(4)));

// ---------------------------------------------------------------------------
// X-tile loader: float input (x, y) or uint8 input (binary spikes s)
// ---------------------------------------------------------------------------
template <typename XT>
__device__ inline float4 load_x4(const XT* p);
template <>
__device__ inline float4 load_x4<float>(const float* p) { return *(const float4*)p; }
template <>
__device__ inline float4 load_x4<uint8_t>(const uint8_t* p) {
  uchar4 u = *(const uchar4*)p;
  return make_float4((float)u.x, (float)u.y, (float)u.z, (float)u.w);
}

// ---------------------------------------------------------------------------
// conv1x1 GEMM, fp64 accumulation on the MATRIX pipe (v_mfma_f64_16x16x4_f64).
//   H[tb][o][n] = sum_c W[o][c] * X[tb][c][n]
// fp32 products are exact in fp64; MFMA-f64 is a true fp64 FMA accumulate.
//
// Round-4 structure: LDS stores DOUBLES (cvt once at staging), permuted
// layouts so fragments are contiguous, double-buffered with ONE barrier per
// K-step and global prefetch issued before the MFMA burst.
//   A LDS: As[buf][o][perm(k)]  perm(k)=4*(k&3)+(k>>2); row pad to 18 doubles
//          -> wave reads its 4 A values (kk=0..3) as 4 contiguous doubles.
//   B LDS: Bs[buf][k][perm(n)]  perm(n)=4*(n&15)+(n>>4); row pad to 66
//          -> wave reads its 4 B values (t=0..3)   as 4 contiguous doubles.
// D layout probed at runtime (worked in round 3): p1=mfma(lane,1,0) ->
// (p1[r]-96)/4 = row.
// Epilogue: store H + per-channel (sum,sumsq) partials (indexed, no atomics).
// ---------------------------------------------------------------------------
template <typename XT>
__global__ __launch_bounds__(256) void conv_gemm_mfma(const float* __restrict__ W,
                                                      const XT* __restrict__ X,
                                                      double* __restrict__ Hout,
                                                      double* __restrict__ Psum,
                                                      double* __restrict__ Psq) {
  __shared__ double As[2][64][18];  // 18432 B
  __shared__ double Bs[2][16][66];  // 16896 B
  const int n0 = blockIdx.x * 64;
  const int o0 = blockIdx.y * 64;
  const int tb = blockIdx.z;
  const int tid = (int)threadIdx.x;
  const int wv = tid >> 6;       // wave 0..3
  const int lane = tid & 63;
  const int l15 = lane & 15;
  const int g = lane >> 4;       // k-group 0..3

  // ---- runtime D-layout probe ----
  int rowmap[4];
  {
    v4d p1 = (v4d){0.0, 0.0, 0.0, 0.0};
    p1 = __builtin_amdgcn_mfma_f64_16x16x4f64((double)lane, 1.0, p1, 0, 0, 0);
#pragma unroll
    for (int r = 0; r < 4; ++r) {
      int rm = (int)((p1[r] - 96.0) * 0.25 + 0.5);
      rowmap[r] = rm < 0 ? 0 : (rm > 15 ? 15 : rm);
    }
  }

  // staging indices
  const int aw_o = tid >> 2;            // 0..63 (o row for W load)
  const int aw_m = tid & 3;             // W cols: k = 4*aw_m + j  -> perm = 4j + aw_m
  const int bx_c = tid >> 4;            // 0..15 (k row for X load)
  const int bx_m = tid & 15;            // X cols: n = 4*bx_m + j
  const int bperm0 = 16 * (bx_m & 3) + (bx_m >> 2);  // perm(n) = bperm0 + 4j

  const float* Wp = W + (size_t)(o0 + aw_o) * C_ + aw_m * 4;
  const XT* Xp = X + ((size_t)(tb * C_ + bx_c)) * N_ + n0 + bx_m * 4;

  v4d acc[4];
#pragma unroll
  for (int t = 0; t < 4; ++t) acc[t] = (v4d){0.0, 0.0, 0.0, 0.0};

  // ---- prologue: stage K-step 0 into buffer 0 ----
  {
    const float4 w4 = *(const float4*)(Wp);
    const float4 xv = load_x4<XT>(Xp);
    As[0][aw_o][4 * 0 + aw_m] = (double)w4.x;
    As[0][aw_o][4 * 1 + aw_m] = (double)w4.y;
    As[0][aw_o][4 * 2 + aw_m] = (double)w4.z;
    As[0][aw_o][4 * 3 + aw_m] = (double)w4.w;
    Bs[0][bx_c][bperm0 + 0]  = (double)xv.x;
    Bs[0][bx_c][bperm0 + 4]  = (double)xv.y;
    Bs[0][bx_c][bperm0 + 8]  = (double)xv.z;
    Bs[0][bx_c][bperm0 + 12] = (double)xv.w;
  }
  __syncthreads();

  for (int step = 0; step < 16; ++step) {
    const int buf = step & 1;
    // prefetch next K-tile from global BEFORE the MFMA burst
    float4 w4n, xvn;
    if (step < 15) {
      w4n = *(const float4*)(Wp + (step + 1) * 16);
      xvn = load_x4<XT>(Xp + (size_t)(step + 1) * 16 * N_);
    }
    // MFMA burst on current buffer
    const double* arow = &As[buf][16 * wv + l15][4 * g];
#pragma unroll
    for (int kk = 0; kk < 4; ++kk) {
      const double a = arow[kk];
      const double* bp = &Bs[buf][4 * kk + g][4 * l15];
#pragma unroll
      for (int t = 0; t < 4; ++t) {
        acc[t] = __builtin_amdgcn_mfma_f64_16x16x4f64(a, bp[t], acc[t], 0, 0, 0);
      }
    }
    // stage next tile into the other buffer; single barrier per K-step
    if (step < 15) {
      const int nb = buf ^ 1;
      As[nb][aw_o][4 * 0 + aw_m] = (double)w4n.x;
      As[nb][aw_o][4 * 1 + aw_m] = (double)w4n.y;
      As[nb][aw_o][4 * 2 + aw_m] = (double)w4n.z;
      As[nb][aw_o][4 * 3 + aw_m] = (double)w4n.w;
      Bs[nb][bx_c][bperm0 + 0]  = (double)xvn.x;
      Bs[nb][bx_c][bperm0 + 4]  = (double)xvn.y;
      Bs[nb][bx_c][bperm0 + 8]  = (double)xvn.z;
      Bs[nb][bx_c][bperm0 + 12] = (double)xvn.w;
      __syncthreads();
    }
  }

  // ---- epilogue: store H, accumulate per-channel partial stats ----
  double s[4] = {0.0, 0.0, 0.0, 0.0};
  double q[4] = {0.0, 0.0, 0.0, 0.0};
#pragma unroll
  for (int t = 0; t < 4; ++t) {
#pragma unroll
    for (int r = 0; r < 4; ++r) {
      const double v = acc[t][r];
      const int row = o0 + 16 * wv + rowmap[r];
      Hout[((size_t)(tb * C_ + row)) * N_ + n0 + 16 * t + l15] = v;
      s[r] += v;
      q[r] += v * v;
    }
  }
  // butterfly over low 4 lane bits: rowmap is uniform within a k-group, so
  // this sums the full 64 columns for each of the group's 4 rows.
#pragma unroll
  for (int m = 1; m < 16; m <<= 1) {
#pragma unroll
    for (int r = 0; r < 4; ++r) {
      s[r] += __shfl_xor(s[r], m);
      q[r] += __shfl_xor(q[r], m);
    }
  }
  if (l15 < 4) {
    const int r = l15;
    const int c = o0 + 16 * wv + rowmap[r];
    const int slot = tb * 32 + (int)blockIdx.x;
    Psum[(size_t)c * NSLOT + slot] = s[r];
    Psq[(size_t)c * NSLOT + slot] = q[r];
  }
}

// ---------------------------------------------------------------------------
// Finalize BN stats: one block per channel, reduce NSLOT partials (fp64).
// ---------------------------------------------------------------------------
__global__ __launch_bounds__(256) void finalize_stats(const double* __restrict__ Psum,
                                                      const double* __restrict__ Psq,
                                                      double* __restrict__ mean,
                                                      double* __restrict__ invstd) {
  const int c = blockIdx.x;
  const int tid = (int)threadIdx.x;
  double s = 0.0, q = 0.0;
  for (int i = tid; i < NSLOT; i += 256) {
    s += Psum[(size_t)c * NSLOT + i];
    q += Psq[(size_t)c * NSLOT + i];
  }
#pragma unroll
  for (int m = 1; m < 64; m <<= 1) {
    s += __shfl_xor(s, m);
    q += __shfl_xor(q, m);
  }
  __shared__ double ls[4], lq[4];
  if ((tid & 63) == 0) {
    ls[tid >> 6] = s;
    lq[tid >> 6] = q;
  }
  __syncthreads();
  if (tid == 0) {
    const double S = ls[0] + ls[1] + ls[2] + ls[3];
    const double Q = lq[0] + lq[1] + lq[2] + lq[3];
    const double m = S / (double)NTOT;
    const double var = Q / (double)NTOT - m * m;
    mean[c] = m;
    invstd[c] = 1.0 / sqrt(var + EPS);
  }
}

// ---------------------------------------------------------------------------
// BN-normalize + spike (>= 1.0), 8 elements per thread.
// OT = uint8_t (intermediate spike maps) or float (final output).
// ---------------------------------------------------------------------------
template <typename OT>
__device__ inline void store8(OT* p, const int* sp);
template <>
__device__ inline void store8<uint8_t>(uint8_t* p, const int* sp) {
  uint64_t w = 0;
#pragma unroll
  for (int j = 0; j < 8; ++j) w |= ((uint64_t)(uint8_t)sp[j]) << (8 * j);
  *(uint64_t*)p = w;
}
template <>
__device__ inline void store8<float>(float* p, const int* sp) {
  float4 a = make_float4((float)sp[0], (float)sp[1], (float)sp[2], (float)sp[3]);
  float4 b = make_float4((float)sp[4], (float)sp[5], (float)sp[6], (float)sp[7]);
  *(float4*)p = a;
  *(float4*)(p + 4) = b;
}

template <typename OT>
__global__ __launch_bounds__(256) void spike_kernel(const double* __restrict__ Hh,
                                                    const float* __restrict__ gamma,
                                                    const float* __restrict__ beta,
                                                    const double* __restrict__ mean,
                                                    const double* __restrict__ invstd,
                                                    OT* __restrict__ out) {
  const size_t i0 = ((size_t)blockIdx.x * 256 + threadIdx.x) * 8;
  const int c = (int)((i0 >> 11) & 255);  // N_=2048 -> 8 consecutive share channel
  const double gm = (double)gamma[c];
  const double bt = (double)beta[c];
  const double mu = mean[c];
  const double is = invstd[c];
  int sp[8];
#pragma unroll
  for (int j = 0; j < 8; ++j) {
    const double v = gm * (Hh[i0 + j] - mu) * is + bt;
    sp[j] = (v >= 1.0) ? 1 : 0;
  }
  store8<OT>(out + i0, sp);
}

// ---------------------------------------------------------------------------
// Linear attention, all-binary operands -> exact integer arithmetic.
// ---------------------------------------------------------------------------
__global__ __launch_bounds__(256) void attn_kernel(const uint8_t* __restrict__ Sq,
                                                   const uint8_t* __restrict__ Sk,
                                                   const uint8_t* __restrict__ Sv,
                                                   uint8_t* __restrict__ Sout) {
  __shared__ float kvs[16][17];
  const int tb = (int)blockIdx.x >> 4;
  const int h = (int)blockIdx.x & 15;
  const size_t base = ((size_t)(tb * C_ + h * D_)) * N_;
  const int tid = (int)threadIdx.x;
  {
    const int d = tid >> 4, e = tid & 15;
    const uint32_t* kr = (const uint32_t*)(Sk + base + (size_t)d * N_);
    const uint32_t* vr = (const uint32_t*)(Sv + base + (size_t)e * N_);
    int cnt = 0;
    for (int i = 0; i < N_ / 4; ++i) cnt += __popc(kr[i] & vr[i]);
    kvs[d][e] = (float)cnt;
  }
  __syncthreads();
  for (int rep = 0; rep < 8; ++rep) {
    const int n = rep * 256 + tid;
    float qv[16];
#pragma unroll
    for (int d = 0; d < 16; ++d) qv[d] = (float)Sq[base + (size_t)d * N_ + n];
#pragma unroll
    for (int e = 0; e < 16; ++e) {
      float acc = 0.f;
#pragma unroll
      for (int d = 0; d < 16; ++d) acc += qv[d] * kvs[d][e];
      Sout[base + (size_t)e * N_ + n] = (0.25f * acc >= 0.5f) ? (uint8_t)1 : (uint8_t)0;
    }
  }
}

// ---------------------------------------------------------------------------
// Launcher. ws layout (bytes) — max offset 192 MB (proven footprint):
//   [0, 128M)       h64 double[16M] (reused by all 4 convs)
//   [128M, 144M)    Sq u8[16M]
//   [144M, 160M)    Sk u8[16M]
//   [160M, 176M)    Sv u8[16M]
//   [176M, 192M)    Sbuf u8[16M]
// Stats scratch (~4M) OVERLAID in dead regions:
//   Q/K/V stages -> inside Sbuf's region (Sbuf only written later by attn)
//   proj stage   -> inside Sq's region  (Sq dead after attn)
// ---------------------------------------------------------------------------
extern "C" void kernel_launch(void* const* d_in, const int* in_sizes, int n_in,
                              void* d_out, int out_size, void* d_ws, size_t ws_size,
                              hipStream_t stream) {
  const float* x   = (const float*)d_in[0];
  const float* y   = (const float*)d_in[1];
  const float* q_w = (const float*)d_in[2];
  const float* q_g = (const float*)d_in[3];
  const float* q_b = (const float*)d_in[4];
  const float* k_w = (const float*)d_in[5];
  const float* k_g = (const float*)d_in[6];
  const float* k_b = (const float*)d_in[7];
  const float* v_w = (const float*)d_in[8];
  const float* v_g = (const float*)d_in[9];
  const float* v_b = (const float*)d_in[10];
  const float* p_w = (const float*)d_in[11];
  const float* p_g = (const float*)d_in[12];
  const float* p_b = (const float*)d_in[13];
  float* out = (float*)d_out;

  char* ws = (char*)d_ws;
  const size_t NE = (size_t)TB_ * C_ * N_;  // 16,777,216
  double* h64   = (double*)ws;
  uint8_t* Sq   = (uint8_t*)(ws + NE * 8);
  uint8_t* Sk   = Sq + NE;
  uint8_t* Sv   = Sk + NE;
  uint8_t* Sbuf = Sv + NE;

  // stats scratch A: overlaid at start of Sbuf region (Q/K/V stages)
  double* PsumA   = (double*)Sbuf;
  double* PsqA    = PsumA + (size_t)C_ * NSLOT;
  double* meanA   = PsqA + (size_t)C_ * NSLOT;
  double* invstdA = meanA + C_;
  // stats scratch B: overlaid at start of Sq region (proj stage)
  double* PsumB   = (double*)Sq;
  double* PsqB    = PsumB + (size_t)C_ * NSLOT;
  double* meanB   = PsqB + (size_t)C_ * NSLOT;
  double* invstdB = meanB + C_;

  const dim3 gridG(N_ / 64, C_ / 64, TB_);  // 32,4,32
  const dim3 blk(256);
  const int spikeBlocks = (int)(NE / (256 * 8));  // 8192

  // --- Q from x ---
  conv_gemm_mfma<float><<<gridG, blk, 0, stream>>>(q_w, x, h64, PsumA, PsqA);
  finalize_stats<<<C_, blk, 0, stream>>>(PsumA, PsqA, meanA, invstdA);
  spike_kernel<uint8_t><<<spikeBlocks, blk, 0, stream>>>(h64, q_g, q_b, meanA, invstdA, Sq);
  // --- K from y ---
  conv_gemm_mfma<float><<<gridG, blk, 0, stream>>>(k_w, y, h64, PsumA, PsqA);
  finalize_stats<<<C_, blk, 0, stream>>>(PsumA, PsqA, meanA, invstdA);
  spike_kernel<uint8_t><<<spikeBlocks, blk, 0, stream>>>(h64, k_g, k_b, meanA, invstdA, Sk);
  // --- V from y ---
  conv_gemm_mfma<float><<<gridG, blk, 0, stream>>>(v_w, y, h64, PsumA, PsqA);
  finalize_stats<<<C_, blk, 0, stream>>>(PsumA, PsqA, meanA, invstdA);
  spike_kernel<uint8_t><<<spikeBlocks, blk, 0, stream>>>(h64, v_g, v_b, meanA, invstdA, Sv);
  // --- attention (exact integer path; overwrites stats scratch A = fine) ---
  attn_kernel<<<TB_ * H_, blk, 0, stream>>>(Sq, Sk, Sv, Sbuf);
  // --- proj (stats scratch B lives in Sq's region, dead after attn) ---
  conv_gemm_mfma<uint8_t><<<gridG, blk, 0, stream>>>(p_w, Sbuf, h64, PsumB, PsqB);
  finalize_stats<<<C_, blk, 0, stream>>>(PsumB, PsqB, meanB, invstdB);
  spike_kernel<float><<<spikeBlocks, blk, 0, stream>>>(h64, p_g, p_b, meanB, invstdB, out);
}

// Round 5
// 964.365 us; speedup vs baseline: 1.0500x; 1.0500x over previous
//
#include <hip/hip_runtime.h>
#include <stdint.h>
#include <math.h>

// Problem dims
#define T_ 4
#define B_ 8
#define C_ 256
#define N_ 2048
#define TB_ 32          // T_*B_
#define H_ 16
#define D_ 16
#define NTOT 65536      // T_*B_*N_  (BN reduction count per channel)
#define EPS 1e-5
#define NSLOT 1024      // per-channel partial-stat slots = n_blocks(32) * tb(32)

typedef int v4i __attribute__((ext_vector_type(4)));

// 2^44, 2^48 scales; digit extraction helpers (balanced base-256 digits).
#define SX_SCALE 17592186044416.0      // 2^44
#define SW_SCALE 281474976710656.0     // 2^48

// ---------------------------------------------------------------------------
// W-limb prep: decompose up to 3 fp32 256x256 matrices into 6 balanced i8
// limb planes each: out[m][limb][o][c], W_int = rint(W*2^48), LSB-first
// digits d_L in [-128,127], W = 2^-48 * sum_L d_L * 256^L (exact).
// grid (256, nmat), block 256: o = blockIdx.x, c = tid.
// ---------------------------------------------------------------------------
__global__ __launch_bounds__(256) void wprep_kernel(const float* __restrict__ W0,
                                                    const float* __restrict__ W1,
                                                    const float* __restrict__ W2,
                                                    int8_t* __restrict__ out) {
  const float* Wm = (blockIdx.y == 0) ? W0 : ((blockIdx.y == 1) ? W1 : W2);
  const int o = blockIdx.x;
  const int c = (int)threadIdx.x;
  double rr = rint((double)Wm[o * C_ + c] * SW_SCALE);
  int8_t* base = out + (size_t)blockIdx.y * 6 * C_ * C_;
#pragma unroll
  for (int L = 0; L < 6; ++L) {
    const double q = floor(fma(rr, 0.00390625, 0.5));
    const double d = fma(q, -256.0, rr);
    base[(size_t)L * C_ * C_ + o * C_ + c] = (int8_t)(int)d;
    rr = q;
  }
}

// ---------------------------------------------------------------------------
// conv1x1 GEMM via exact i8 fixed-point (Ozaki scheme) on mfma_i32_16x16x64_i8.
//   H[tb][o][n] = sum_c W[o][c] * X[tb][c][n]
// W: 6 limbs (precomputed planes Wl[limb][o][c], scale 2^-48)
// X: 6 limbs (extracted on the fly into LDS, scale 2^-44, layout [limb][n][c])
// Keep limb pairs with i+j >= 5 (21 pairs); accumulate per e=i+j in i32
// (exact, max |sum| ~ 4.2M << 2^31); recombine h = sum_e Acc_e * 2^(8e-92).
// Error vs exact fp64: sigma ~3e-13 -> spike-flip probability ~5e-6 total.
//
// Fragment layouts (gfx950, HW-verified family): A m=lane&15, k=16*(lane>>4)+j
// (k-contiguous bytes); B n=lane&15, same k packing -> any HW k-permutation
// cancels between A and B. C/D: col=lane&15, row=4*(lane>>4)+reg (m121-128).
//
// Block: 256 thr (4 waves), 64(o) x 64(n) tile; wave wv -> o rows [16wv,+16),
// 4 n-subtiles. K=256 in 4 slabs of 64. A-frags direct from global (L2-hot,
// 16B/lane). Grid (32, 4, 32).
// ---------------------------------------------------------------------------
__global__ __launch_bounds__(256) void conv_i8_qkv(const int8_t* __restrict__ Wl,
                                                   const float* __restrict__ X,
                                                   double* __restrict__ Hout,
                                                   double* __restrict__ Psum,
                                                   double* __restrict__ Psq) {
  __shared__ int8_t Xls[6][64][80];   // [limb][n][c], row stride 80 (2-way alias = free)
  const int n0 = blockIdx.x * 64;
  const int o0 = blockIdx.y * 64;
  const int tb = blockIdx.z;
  const int tid = (int)threadIdx.x;
  const int wv = tid >> 6;
  const int lane = tid & 63;
  const int l15 = lane & 15;
  const int g = lane >> 4;

  const int c_l = tid >> 2;   // 0..63 (c row this thread stages)
  const int nc  = tid & 3;    // n-chunk (16 n per chunk)

  v4i acc[4][6] = {};          // [n-subtile][e = i+j-5]

  for (int slab = 0; slab < 4; ++slab) {
    const int c0 = slab * 64;
    // A-frags direct from global: Wl[limb][o0+16wv+l15][c0+16g .. +16)
    v4i A[6];
#pragma unroll
    for (int i = 0; i < 6; ++i)
      A[i] = *(const v4i*)(Wl + ((size_t)i * C_ + o0 + 16 * wv + l15) * C_ + c0 + 16 * g);

    __syncthreads();  // previous slab's B reads done
    // stage X digits: load fp32 [c][n] coalesced, extract 6 limbs, scatter
    // transposed into Xls[limb][n][c].
    {
      const float* xp = X + ((size_t)(tb * C_ + c0 + c_l)) * N_ + n0 + nc * 16;
#pragma unroll
      for (int r = 0; r < 4; ++r) {
        const float4 xv = *(const float4*)(xp + 4 * r);
        const float vs[4] = {xv.x, xv.y, xv.z, xv.w};
#pragma unroll
        for (int j = 0; j < 4; ++j) {
          double rr = rint((double)vs[j] * SX_SCALE);
          const int nl = nc * 16 + 4 * r + j;
#pragma unroll
          for (int L = 0; L < 6; ++L) {
            const double q = floor(fma(rr, 0.00390625, 0.5));
            const double d = fma(q, -256.0, rr);
            Xls[L][nl][c_l] = (int8_t)(int)d;
            rr = q;
          }
        }
      }
    }
    __syncthreads();

#pragma unroll
    for (int t = 0; t < 4; ++t) {
      v4i Bf[6];
#pragma unroll
      for (int j = 0; j < 6; ++j)
        Bf[j] = *(const v4i*)&Xls[j][16 * t + l15][16 * g];
      // 21 MFMAs, j-descending order interleaves the 6 e-accumulators
#pragma unroll
      for (int j = 5; j >= 0; --j)
#pragma unroll
        for (int i = 5 - j; i < 6; ++i)
          acc[t][i + j - 5] =
              __builtin_amdgcn_mfma_i32_16x16x64_i8(A[i], Bf[j], acc[t][i + j - 5], 0, 0, 0);
    }
  }

  // ---- epilogue: recombine, store H, per-channel partial stats ----
  const double scale[6] = {0x1p-52, 0x1p-44, 0x1p-36, 0x1p-28, 0x1p-20, 0x1p-12};
  double s[4] = {0.0, 0.0, 0.0, 0.0};
  double q[4] = {0.0, 0.0, 0.0, 0.0};
#pragma unroll
  for (int t = 0; t < 4; ++t) {
#pragma unroll
    for (int r = 0; r < 4; ++r) {
      double v = 0.0;
#pragma unroll
      for (int a = 0; a < 6; ++a) v = fma(scale[a], (double)acc[t][a][r], v);
      const int row = o0 + 16 * wv + 4 * g + r;   // D: col=lane&15, row=4*(lane>>4)+reg
      Hout[((size_t)(tb * C_ + row)) * N_ + n0 + 16 * t + l15] = v;
      s[r] += v;
      q[r] += v * v;
    }
  }
#pragma unroll
  for (int m = 1; m < 16; m <<= 1) {
#pragma unroll
    for (int r = 0; r < 4; ++r) {
      s[r] += __shfl_xor(s[r], m);
      q[r] += __shfl_xor(q[r], m);
    }
  }
  if (l15 < 4) {
    const int r = l15;
    const int c = o0 + 16 * wv + 4 * g + r;
    const int slot = tb * 32 + (int)blockIdx.x;
    Psum[(size_t)c * NSLOT + slot] = s[r];
    Psq[(size_t)c * NSLOT + slot] = q[r];
  }
}

// ---------------------------------------------------------------------------
// proj conv: X is a binary spike map (u8 in {0,1}) -> single exact limb.
// 6 MFMAs per slab (one per W limb); h = sum_i Acc_i * 2^(8i-48), exact.
// ---------------------------------------------------------------------------
__global__ __launch_bounds__(256) void conv_i8_proj(const int8_t* __restrict__ Wl,
                                                    const uint8_t* __restrict__ S,
                                                    double* __restrict__ Hout,
                                                    double* __restrict__ Psum,
                                                    double* __restrict__ Psq) {
  __shared__ int8_t X1s[64][80];   // [n][c]
  const int n0 = blockIdx.x * 64;
  const int o0 = blockIdx.y * 64;
  const int tb = blockIdx.z;
  const int tid = (int)threadIdx.x;
  const int wv = tid >> 6;
  const int lane = tid & 63;
  const int l15 = lane & 15;
  const int g = lane >> 4;

  const int c_l = tid >> 2;
  const int nc  = tid & 3;

  v4i acc[4][6] = {};   // [n-subtile][W limb]

  for (int slab = 0; slab < 4; ++slab) {
    const int c0 = slab * 64;
    v4i A[6];
#pragma unroll
    for (int i = 0; i < 6; ++i)
      A[i] = *(const v4i*)(Wl + ((size_t)i * C_ + o0 + 16 * wv + l15) * C_ + c0 + 16 * g);

    __syncthreads();
    {
      // load 16 spike bytes along n (coalesced 16B), scatter transposed
      const int4 sv = *(const int4*)(S + ((size_t)(tb * C_ + c0 + c_l)) * N_ + n0 + nc * 16);
      const int8_t* sb = (const int8_t*)&sv;
#pragma unroll
      for (int j = 0; j < 16; ++j) X1s[nc * 16 + j][c_l] = sb[j];
    }
    __syncthreads();

#pragma unroll
    for (int t = 0; t < 4; ++t) {
      const v4i Bf = *(const v4i*)&X1s[16 * t + l15][16 * g];
#pragma unroll
      for (int i = 0; i < 6; ++i)
        acc[t][i] = __builtin_amdgcn_mfma_i32_16x16x64_i8(A[i], Bf, acc[t][i], 0, 0, 0);
    }
  }

  const double scale[6] = {0x1p-48, 0x1p-40, 0x1p-32, 0x1p-24, 0x1p-16, 0x1p-8};
  double s[4] = {0.0, 0.0, 0.0, 0.0};
  double q[4] = {0.0, 0.0, 0.0, 0.0};
#pragma unroll
  for (int t = 0; t < 4; ++t) {
#pragma unroll
    for (int r = 0; r < 4; ++r) {
      double v = 0.0;
#pragma unroll
      for (int a = 0; a < 6; ++a) v = fma(scale[a], (double)acc[t][a][r], v);
      const int row = o0 + 16 * wv + 4 * g + r;
      Hout[((size_t)(tb * C_ + row)) * N_ + n0 + 16 * t + l15] = v;
      s[r] += v;
      q[r] += v * v;
    }
  }
#pragma unroll
  for (int m = 1; m < 16; m <<= 1) {
#pragma unroll
    for (int r = 0; r < 4; ++r) {
      s[r] += __shfl_xor(s[r], m);
      q[r] += __shfl_xor(q[r], m);
    }
  }
  if (l15 < 4) {
    const int r = l15;
    const int c = o0 + 16 * wv + 4 * g + r;
    const int slot = tb * 32 + (int)blockIdx.x;
    Psum[(size_t)c * NSLOT + slot] = s[r];
    Psq[(size_t)c * NSLOT + slot] = q[r];
  }
}

// ---------------------------------------------------------------------------
// Finalize BN stats: one block per channel, reduce NSLOT partials (fp64).
// ---------------------------------------------------------------------------
__global__ __launch_bounds__(256) void finalize_stats(const double* __restrict__ Psum,
                                                      const double* __restrict__ Psq,
                                                      double* __restrict__ mean,
                                                      double* __restrict__ invstd) {
  const int c = blockIdx.x;
  const int tid = (int)threadIdx.x;
  double s = 0.0, q = 0.0;
  for (int i = tid; i < NSLOT; i += 256) {
    s += Psum[(size_t)c * NSLOT + i];
    q += Psq[(size_t)c * NSLOT + i];
  }
#pragma unroll
  for (int m = 1; m < 64; m <<= 1) {
    s += __shfl_xor(s, m);
    q += __shfl_xor(q, m);
  }
  __shared__ double ls[4], lq[4];
  if ((tid & 63) == 0) {
    ls[tid >> 6] = s;
    lq[tid >> 6] = q;
  }
  __syncthreads();
  if (tid == 0) {
    const double S = ls[0] + ls[1] + ls[2] + ls[3];
    const double Q = lq[0] + lq[1] + lq[2] + lq[3];
    const double m = S / (double)NTOT;
    const double var = Q / (double)NTOT - m * m;
    mean[c] = m;
    invstd[c] = 1.0 / sqrt(var + EPS);
  }
}

// ---------------------------------------------------------------------------
// BN-normalize + spike (>= 1.0), 8 elements per thread.
// ---------------------------------------------------------------------------
template <typename OT>
__device__ inline void store8(OT* p, const int* sp);
template <>
__device__ inline void store8<uint8_t>(uint8_t* p, const int* sp) {
  uint64_t w = 0;
#pragma unroll
  for (int j = 0; j < 8; ++j) w |= ((uint64_t)(uint8_t)sp[j]) << (8 * j);
  *(uint64_t*)p = w;
}
template <>
__device__ inline void store8<float>(float* p, const int* sp) {
  float4 a = make_float4((float)sp[0], (float)sp[1], (float)sp[2], (float)sp[3]);
  float4 b = make_float4((float)sp[4], (float)sp[5], (float)sp[6], (float)sp[7]);
  *(float4*)p = a;
  *(float4*)(p + 4) = b;
}

template <typename OT>
__global__ __launch_bounds__(256) void spike_kernel(const double* __restrict__ Hh,
                                                    const float* __restrict__ gamma,
                                                    const float* __restrict__ beta,
                                                    const double* __restrict__ mean,
                                                    const double* __restrict__ invstd,
                                                    OT* __restrict__ out) {
  const size_t i0 = ((size_t)blockIdx.x * 256 + threadIdx.x) * 8;
  const int c = (int)((i0 >> 11) & 255);
  const double gm = (double)gamma[c];
  const double bt = (double)beta[c];
  const double mu = mean[c];
  const double is = invstd[c];
  int sp[8];
#pragma unroll
  for (int j = 0; j < 8; ++j) {
    const double v = gm * (Hh[i0 + j] - mu) * is + bt;
    sp[j] = (v >= 1.0) ? 1 : 0;
  }
  store8<OT>(out + i0, sp);
}

// ---------------------------------------------------------------------------
// Linear attention, all-binary operands -> exact integer arithmetic.
// ---------------------------------------------------------------------------
__global__ __launch_bounds__(256) void attn_kernel(const uint8_t* __restrict__ Sq,
                                                   const uint8_t* __restrict__ Sk,
                                                   const uint8_t* __restrict__ Sv,
                                                   uint8_t* __restrict__ Sout) {
  __shared__ float kvs[16][17];
  const int tb = (int)blockIdx.x >> 4;
  const int h = (int)blockIdx.x & 15;
  const size_t base = ((size_t)(tb * C_ + h * D_)) * N_;
  const int tid = (int)threadIdx.x;
  {
    const int d = tid >> 4, e = tid & 15;
    const uint32_t* kr = (const uint32_t*)(Sk + base + (size_t)d * N_);
    const uint32_t* vr = (const uint32_t*)(Sv + base + (size_t)e * N_);
    int cnt = 0;
    for (int i = 0; i < N_ / 4; ++i) cnt += __popc(kr[i] & vr[i]);
    kvs[d][e] = (float)cnt;
  }
  __syncthreads();
  for (int rep = 0; rep < 8; ++rep) {
    const int n = rep * 256 + tid;
    float qv[16];
#pragma unroll
    for (int d = 0; d < 16; ++d) qv[d] = (float)Sq[base + (size_t)d * N_ + n];
#pragma unroll
    for (int e = 0; e < 16; ++e) {
      float acc = 0.f;
#pragma unroll
      for (int d = 0; d < 16; ++d) acc += qv[d] * kvs[d][e];
      Sout[base + (size_t)e * N_ + n] = (0.25f * acc >= 0.5f) ? (uint8_t)1 : (uint8_t)0;
    }
  }
}

// ---------------------------------------------------------------------------
// Launcher. ws layout (bytes) — max offset 192 MB (proven footprint):
//   [0, 128M)       h64 double[16M] (reused by all 4 convs)
//   [128M, 144M)    Sq u8[16M]
//   [144M, 160M)    Sk u8[16M]
//   [160M, 176M)    Sv u8[16M]
//   [176M, 192M)    Sbuf u8[16M]
// Overlays in dead regions:
//   statsA (4M)   at Sbuf+0   (dead until attn writes Sbuf)
//   WlA (3x384KB) at Sbuf+8M  (q/k/v W limbs; dead once attn runs)
//   statsB (4M)   at Sq+0     (Sq dead after attn)
//   WlB (384KB)   at Sq+8M    (proj W limbs, prepped after attn)
// ---------------------------------------------------------------------------
extern "C" void kernel_launch(void* const* d_in, const int* in_sizes, int n_in,
                              void* d_out, int out_size, void* d_ws, size_t ws_size,
                              hipStream_t stream) {
  const float* x   = (const float*)d_in[0];
  const float* y   = (const float*)d_in[1];
  const float* q_w = (const float*)d_in[2];
  const float* q_g = (const float*)d_in[3];
  const float* q_b = (const float*)d_in[4];
  const float* k_w = (const float*)d_in[5];
  const float* k_g = (const float*)d_in[6];
  const float* k_b = (const float*)d_in[7];
  const float* v_w = (const float*)d_in[8];
  const float* v_g = (const float*)d_in[9];
  const float* v_b = (const float*)d_in[10];
  const float* p_w = (const float*)d_in[11];
  const float* p_g = (const float*)d_in[12];
  const float* p_b = (const float*)d_in[13];
  float* out = (float*)d_out;

  char* ws = (char*)d_ws;
  const size_t NE = (size_t)TB_ * C_ * N_;  // 16,777,216
  double* h64   = (double*)ws;
  uint8_t* Sq   = (uint8_t*)(ws + NE * 8);
  uint8_t* Sk   = Sq + NE;
  uint8_t* Sv   = Sk + NE;
  uint8_t* Sbuf = Sv + NE;

  // statsA overlay at Sbuf; W-limb planes for q/k/v at Sbuf+8M
  double* PsumA   = (double*)Sbuf;
  double* PsqA    = PsumA + (size_t)C_ * NSLOT;
  double* meanA   = PsqA + (size_t)C_ * NSLOT;
  double* invstdA = meanA + C_;
  int8_t* WlA     = (int8_t*)(Sbuf + 8 * 1024 * 1024);
  int8_t* Wl_q    = WlA;
  int8_t* Wl_k    = WlA + (size_t)6 * C_ * C_;
  int8_t* Wl_v    = WlA + (size_t)12 * C_ * C_;
  // statsB overlay at Sq; proj W limbs at Sq+8M
  double* PsumB   = (double*)Sq;
  double* PsqB    = PsumB + (size_t)C_ * NSLOT;
  double* meanB   = PsqB + (size_t)C_ * NSLOT;
  double* invstdB = meanB + C_;
  int8_t* WlB     = (int8_t*)(Sq + 8 * 1024 * 1024);

  const dim3 gridG(N_ / 64, C_ / 64, TB_);  // 32,4,32
  const dim3 blk(256);
  const int spikeBlocks = (int)(NE / (256 * 8));  // 8192

  // --- W-limb prep for q/k/v ---
  wprep_kernel<<<dim3(C_, 3), blk, 0, stream>>>(q_w, k_w, v_w, WlA);
  // --- Q from x ---
  conv_i8_qkv<<<gridG, blk, 0, stream>>>(Wl_q, x, h64, PsumA, PsqA);
  finalize_stats<<<C_, blk, 0, stream>>>(PsumA, PsqA, meanA, invstdA);
  spike_kernel<uint8_t><<<spikeBlocks, blk, 0, stream>>>(h64, q_g, q_b, meanA, invstdA, Sq);
  // --- K from y ---
  conv_i8_qkv<<<gridG, blk, 0, stream>>>(Wl_k, y, h64, PsumA, PsqA);
  finalize_stats<<<C_, blk, 0, stream>>>(PsumA, PsqA, meanA, invstdA);
  spike_kernel<uint8_t><<<spikeBlocks, blk, 0, stream>>>(h64, k_g, k_b, meanA, invstdA, Sk);
  // --- V from y ---
  conv_i8_qkv<<<gridG, blk, 0, stream>>>(Wl_v, y, h64, PsumA, PsqA);
  finalize_stats<<<C_, blk, 0, stream>>>(PsumA, PsqA, meanA, invstdA);
  spike_kernel<uint8_t><<<spikeBlocks, blk, 0, stream>>>(h64, v_g, v_b, meanA, invstdA, Sv);
  // --- attention (overwrites Sbuf region incl. statsA/WlA overlays = fine) ---
  attn_kernel<<<TB_ * H_, blk, 0, stream>>>(Sq, Sk, Sv, Sbuf);
  // --- proj: prep W limbs (into Sq region, dead after attn), conv, spike ---
  wprep_kernel<<<dim3(C_, 1), blk, 0, stream>>>(p_w, p_w, p_w, WlB);
  conv_i8_proj<<<gridG, blk, 0, stream>>>(WlB, Sbuf, h64, PsumB, PsqB);
  finalize_stats<<<C_, blk, 0, stream>>>(PsumB, PsqB, meanB, invstdB);
  spike_kernel<float><<<spikeBlocks, blk, 0, stream>>>(h64, p_g, p_b, meanB, invstdB, out);
}